// Round 2
// baseline (7839.258 us; speedup 1.0000x reference)
//
#include <hip/hip_runtime.h>
#include <math.h>

#define NTOK_TOTAL 32768

// ---------------- LDS layout for token kernel (floats) ----------------
#define O_WQ   0
#define O_WK   576
#define O_WV   1152
#define O_RELK 1728
#define O_RELV 1836
#define O_W1   1944
#define O_W2   4248
#define O_BQ   6552
#define O_BK   6576
#define O_BV   6600
#define O_B1   6624
#define O_B2   6720
#define O_GA   6744
#define O_BA   6768
#define O_GF   6792
#define O_BF   6816
#define O_KV   6840                 // [12 tokens][21][24] reused k then v
#define SM_TOT (O_KV + 12*504)      // 12888 floats = 51552 B -> 3 blocks/CU

// ---------------- kernel 0: positional encoding table (transposed [f][s]) ----------------
__global__ void posenc_kernel(float* __restrict__ pe) {
    int i = threadIdx.x;
    if (i < 504) {
        int f = i / 21, s = i % 21;
        double e = (double)(2 * (f / 2)) / 24.0;
        double ang = (double)s / pow(10000.0, e);
        float v = (f & 1) ? cosf((float)ang) : sinf((float)ang);
        pe[i] = 0.01f * v + 0.01f;   // folded *0.01 + 0.01
    }
}

// ---------------- kernel 1: fused per-token transformer, one row per lane ----------------
__global__ __launch_bounds__(256, 3) void token_kernel(
    const float* __restrict__ inp,
    const float* __restrict__ wq, const float* __restrict__ bq,
    const float* __restrict__ wk, const float* __restrict__ bk,
    const float* __restrict__ wv, const float* __restrict__ bv,
    const float* __restrict__ relk, const float* __restrict__ relv,
    const float* __restrict__ ga, const float* __restrict__ ba,
    const float* __restrict__ w1, const float* __restrict__ b1,
    const float* __restrict__ w2, const float* __restrict__ b2,
    const float* __restrict__ gf, const float* __restrict__ bf,
    const float* __restrict__ pe, float* __restrict__ ffout, int ntok)
{
    __shared__ __align__(16) float sm[SM_TOT];
    const int tid = threadIdx.x;

    // ---- cooperative weight staging (the only __syncthreads) ----
    for (int i = tid; i < 576; i += 256) { sm[O_WQ+i]=wq[i]; sm[O_WK+i]=wk[i]; sm[O_WV+i]=wv[i]; }
    if (tid < 108) { sm[O_RELK+tid]=relk[tid]; sm[O_RELV+tid]=relv[tid]; }
    for (int i = tid; i < 2304; i += 256) { sm[O_W1+i]=w1[i]; sm[O_W2+i]=w2[i]; }
    if (tid < 24) { sm[O_BQ+tid]=bq[tid]; sm[O_BK+tid]=bk[tid]; sm[O_BV+tid]=bv[tid];
                    sm[O_B2+tid]=b2[tid]; sm[O_GA+tid]=ga[tid]; sm[O_BA+tid]=ba[tid];
                    sm[O_GF+tid]=gf[tid]; sm[O_BF+tid]=bf[tid]; }
    if (tid >= 128 && tid < 224) sm[O_B1+tid-128] = b1[tid-128];
    __syncthreads();

    // ---- lane -> (token, row) ----
    const int lane = tid & 63;
    const int wv_  = tid >> 6;
    int t = lane / 21;
    int s = lane - t * 21;
    bool act = (lane < 63);
    if (!act) { t = 2; s = 20; }          // dummy lane mirrors lane 62 (same addrs, benign)
    const int n0 = blockIdx.x * 12 + wv_ * 3 + t;
    const bool wr = act && (n0 < ntok);
    const int n  = (n0 < ntok) ? n0 : (ntok - 1);

    float* myrow = &sm[O_KV + (wv_*3 + t)*504 + s*24];
    const float* ktok = &sm[O_KV + (wv_*3 + t)*504];

    // ---- load x row (+ posenc, prefolded) ----
    float x[24];
    #pragma unroll
    for (int f = 0; f < 24; ++f)
        x[f] = inp[(size_t)n*504 + f*21 + s] + pe[f*21 + s];

    // ---- q,k,v = relu(x @ W + b); k,v to LDS (k first, v kept in regs) ----
    float q[24], v[24];
    {
        #pragma unroll
        for (int fc = 0; fc < 24; fc += 4) {
            float4 b4 = *(const float4*)&sm[O_BQ + fc];
            float a0=b4.x, a1=b4.y, a2=b4.z, a3=b4.w;
            #pragma unroll
            for (int j = 0; j < 24; ++j) {
                float4 w4 = *(const float4*)&sm[O_WQ + j*24 + fc];
                a0 = fmaf(x[j], w4.x, a0); a1 = fmaf(x[j], w4.y, a1);
                a2 = fmaf(x[j], w4.z, a2); a3 = fmaf(x[j], w4.w, a3);
            }
            q[fc]=fmaxf(a0,0.f); q[fc+1]=fmaxf(a1,0.f); q[fc+2]=fmaxf(a2,0.f); q[fc+3]=fmaxf(a3,0.f);
        }
        #pragma unroll
        for (int fc = 0; fc < 24; fc += 4) {     // k -> straight to LDS
            float4 b4 = *(const float4*)&sm[O_BK + fc];
            float a0=b4.x, a1=b4.y, a2=b4.z, a3=b4.w;
            #pragma unroll
            for (int j = 0; j < 24; ++j) {
                float4 w4 = *(const float4*)&sm[O_WK + j*24 + fc];
                a0 = fmaf(x[j], w4.x, a0); a1 = fmaf(x[j], w4.y, a1);
                a2 = fmaf(x[j], w4.z, a2); a3 = fmaf(x[j], w4.w, a3);
            }
            *(float4*)(myrow + fc) = make_float4(fmaxf(a0,0.f), fmaxf(a1,0.f), fmaxf(a2,0.f), fmaxf(a3,0.f));
        }
        #pragma unroll
        for (int fc = 0; fc < 24; fc += 4) {     // v -> registers
            float4 b4 = *(const float4*)&sm[O_BV + fc];
            float a0=b4.x, a1=b4.y, a2=b4.z, a3=b4.w;
            #pragma unroll
            for (int j = 0; j < 24; ++j) {
                float4 w4 = *(const float4*)&sm[O_WV + j*24 + fc];
                a0 = fmaf(x[j], w4.x, a0); a1 = fmaf(x[j], w4.y, a1);
                a2 = fmaf(x[j], w4.z, a2); a3 = fmaf(x[j], w4.w, a3);
            }
            v[fc]=fmaxf(a0,0.f); v[fc+1]=fmaxf(a1,0.f); v[fc+2]=fmaxf(a2,0.f); v[fc+3]=fmaxf(a3,0.f);
        }
    }
    // k writes visible to whole wave (same wave, single PC: drain LDS queue)
    asm volatile("s_waitcnt lgkmcnt(0)" ::: "memory");

    // ---- logits + softmax per head, all in registers ----
    const float rsc = 0.28867513459481287f;   // 1/sqrt(12)
    float p0[21], p1[21];
    #pragma unroll
    for (int h = 0; h < 2; ++h) {
        float* p = h ? p1 : p0;
        float lg[21];
        #pragma unroll
        for (int ks = 0; ks < 21; ++ks) {
            int dd = ks - s; dd = dd < -4 ? -4 : (dd > 4 ? 4 : dd);
            const float4* kr = (const float4*)(ktok + ks*24 + h*12);
            const float4* rr = (const float4*)(&sm[O_RELK + (dd+4)*12]);
            float acc = 0.f;
            #pragma unroll
            for (int c = 0; c < 3; ++c) {
                float4 k4 = kr[c]; float4 r4 = rr[c];
                acc = fmaf(q[h*12+c*4+0], k4.x + r4.x, acc);
                acc = fmaf(q[h*12+c*4+1], k4.y + r4.y, acc);
                acc = fmaf(q[h*12+c*4+2], k4.z + r4.z, acc);
                acc = fmaf(q[h*12+c*4+3], k4.w + r4.w, acc);
            }
            lg[ks] = acc * rsc;
        }
        float m = lg[0];
        #pragma unroll
        for (int ks = 1; ks < 21; ++ks) m = fmaxf(m, lg[ks]);
        float ssum = 0.f;
        #pragma unroll
        for (int ks = 0; ks < 21; ++ks) { float e = __expf(lg[ks]-m); p[ks] = e; ssum += e; }
        float inv = 1.f / ssum;
        #pragma unroll
        for (int ks = 0; ks < 21; ++ks) p[ks] *= inv;
    }

    // ---- publish v into same LDS tile (k reads above are all retired) ----
    asm volatile("s_waitcnt lgkmcnt(0)" ::: "memory");
    #pragma unroll
    for (int fc = 0; fc < 24; fc += 4)
        *(float4*)(myrow + fc) = make_float4(v[fc], v[fc+1], v[fc+2], v[fc+3]);
    asm volatile("s_waitcnt lgkmcnt(0)" ::: "memory");

    // ---- o = p · (v + rel_v); residual ----
    float o[24];
    #pragma unroll
    for (int f = 0; f < 24; ++f) o[f] = 0.f;
    #pragma unroll
    for (int h = 0; h < 2; ++h) {
        const float* p = h ? p1 : p0;
        #pragma unroll
        for (int ks = 0; ks < 21; ++ks) {
            float pw = p[ks];
            int dd = ks - s; dd = dd < -4 ? -4 : (dd > 4 ? 4 : dd);
            const float4* vr = (const float4*)(ktok + ks*24 + h*12);
            const float4* rr = (const float4*)(&sm[O_RELV + (dd+4)*12]);
            #pragma unroll
            for (int c = 0; c < 3; ++c) {
                float4 v4 = vr[c]; float4 r4 = rr[c];
                o[h*12+c*4+0] = fmaf(pw, v4.x + r4.x, o[h*12+c*4+0]);
                o[h*12+c*4+1] = fmaf(pw, v4.y + r4.y, o[h*12+c*4+1]);
                o[h*12+c*4+2] = fmaf(pw, v4.z + r4.z, o[h*12+c*4+2]);
                o[h*12+c*4+3] = fmaf(pw, v4.w + r4.w, o[h*12+c*4+3]);
            }
        }
    }

    // ---- attn = LN(o + x)  (fully lane-local) ----
    float at[24];
    {
        float s1 = 0.f, s2 = 0.f;
        #pragma unroll
        for (int f = 0; f < 24; ++f) { at[f] = o[f] + x[f]; s1 += at[f]; s2 = fmaf(at[f], at[f], s2); }
        float m = s1 * (1.f/24.f);
        float rs = rsqrtf(s2*(1.f/24.f) - m*m + 1e-3f);
        #pragma unroll
        for (int f = 0; f < 24; ++f) at[f] = fmaf(sm[O_GA+f], (at[f]-m)*rs, sm[O_BA+f]);
    }

    // ---- ff = LN( relu(at@w1+b1)@w2 + b2 + at )  in 24-wide hidden chunks ----
    float ffa[24];
    #pragma unroll
    for (int fc = 0; fc < 24; fc += 4) {
        float4 b4 = *(const float4*)&sm[O_B2 + fc];
        ffa[fc]=b4.x; ffa[fc+1]=b4.y; ffa[fc+2]=b4.z; ffa[fc+3]=b4.w;
    }
    #pragma unroll
    for (int cc = 0; cc < 96; cc += 24) {
        float hid[24];
        #pragma unroll
        for (int lc = 0; lc < 24; lc += 4) {
            float4 b4 = *(const float4*)&sm[O_B1 + cc + lc];
            hid[lc]=b4.x; hid[lc+1]=b4.y; hid[lc+2]=b4.z; hid[lc+3]=b4.w;
        }
        #pragma unroll
        for (int j = 0; j < 24; ++j) {
            float xv = at[j];
            #pragma unroll
            for (int lc = 0; lc < 24; lc += 4) {
                float4 w4 = *(const float4*)&sm[O_W1 + j*96 + cc + lc];
                hid[lc]   = fmaf(xv, w4.x, hid[lc]);
                hid[lc+1] = fmaf(xv, w4.y, hid[lc+1]);
                hid[lc+2] = fmaf(xv, w4.z, hid[lc+2]);
                hid[lc+3] = fmaf(xv, w4.w, hid[lc+3]);
            }
        }
        #pragma unroll
        for (int lc = 0; lc < 24; ++lc) hid[lc] = fmaxf(hid[lc], 0.f);
        #pragma unroll
        for (int lc = 0; lc < 24; ++lc) {
            float hv = hid[lc];
            #pragma unroll
            for (int f = 0; f < 24; f += 4) {
                float4 w4 = *(const float4*)&sm[O_W2 + (cc+lc)*24 + f];
                ffa[f]   = fmaf(hv, w4.x, ffa[f]);
                ffa[f+1] = fmaf(hv, w4.y, ffa[f+1]);
                ffa[f+2] = fmaf(hv, w4.z, ffa[f+2]);
                ffa[f+3] = fmaf(hv, w4.w, ffa[f+3]);
            }
        }
    }
    {
        float s1 = 0.f, s2 = 0.f;
        #pragma unroll
        for (int f = 0; f < 24; ++f) { ffa[f] += at[f]; s1 += ffa[f]; s2 = fmaf(ffa[f], ffa[f], s2); }
        float m = s1 * (1.f/24.f);
        float rs = rsqrtf(s2*(1.f/24.f) - m*m + 1e-3f);
        #pragma unroll
        for (int f = 0; f < 24; ++f) ffa[f] = fmaf(sm[O_GF+f], (ffa[f]-m)*rs, sm[O_BF+f]);
    }

    // ---- write transposed: ffout[n][f*21+s] ----
    if (wr) {
        #pragma unroll
        for (int f = 0; f < 24; ++f)
            ffout[(size_t)n0*504 + f*21 + s] = ffa[f];
    }
}

// ---------------- kernel 2: [N,504]@[504,512] + bias + relu + LN(512) ----------------
__global__ __launch_bounds__(256, 3) void dense_ln_kernel(
    const float* __restrict__ A, const float* __restrict__ wd, const float* __restrict__ bd,
    const float* __restrict__ g, const float* __restrict__ b, float* __restrict__ out)
{
    __shared__ float At[24*36];     // transposed+padded A tile [kk][r]
    __shared__ float Bs[24*512];    // B tile [kk][c]
    const int tid = threadIdx.x;
    const int tx = tid & 63, ty = tid >> 6;
    const int row0 = blockIdx.x * 32;

    float acc[8][8];
    #pragma unroll
    for (int r = 0; r < 8; ++r)
        #pragma unroll
        for (int j = 0; j < 8; ++j) acc[r][j] = 0.f;

    for (int k0 = 0; k0 < 504; k0 += 24) {
        __syncthreads();
        for (int i = tid; i < 768; i += 256) {
            int r = i / 24, kk = i % 24;
            At[kk*36 + r] = A[(size_t)(row0 + r)*504 + k0 + kk];
        }
        const float4* Bg = reinterpret_cast<const float4*>(wd + k0*512);
        float4* Bs4 = reinterpret_cast<float4*>(Bs);
        #pragma unroll
        for (int v = 0; v < 12; ++v) Bs4[tid + v*256] = Bg[tid + v*256];
        __syncthreads();

        #pragma unroll 4
        for (int kk = 0; kk < 24; ++kk) {
            float4 a0 = *reinterpret_cast<const float4*>(&At[kk*36 + ty*8]);
            float4 a1 = *reinterpret_cast<const float4*>(&At[kk*36 + ty*8 + 4]);
            float a[8] = {a0.x, a0.y, a0.z, a0.w, a1.x, a1.y, a1.z, a1.w};
            float bv[8];
            #pragma unroll
            for (int j = 0; j < 8; ++j) bv[j] = Bs[kk*512 + tx + 64*j];
            #pragma unroll
            for (int r = 0; r < 8; ++r)
                #pragma unroll
                for (int j = 0; j < 8; ++j)
                    acc[r][j] = fmaf(a[r], bv[j], acc[r][j]);
        }
    }

    // ---- epilogue: bias + relu + LN over 512 (each wave owns whole rows) ----
    float bdv[8], gv[8], bbv[8];
    #pragma unroll
    for (int j = 0; j < 8; ++j) { int c = tx + 64*j; bdv[j]=bd[c]; gv[j]=g[c]; bbv[j]=b[c]; }
    const int rowb = row0 + ty*8;
    #pragma unroll
    for (int r = 0; r < 8; ++r) {
        float v[8]; float s1 = 0.f, s2 = 0.f;
        #pragma unroll
        for (int j = 0; j < 8; ++j) {
            float t = fmaxf(acc[r][j] + bdv[j], 0.f);
            v[j] = t; s1 += t; s2 = fmaf(t, t, s2);
        }
        #pragma unroll
        for (int off = 32; off > 0; off >>= 1) {
            s1 += __shfl_xor(s1, off);
            s2 += __shfl_xor(s2, off);
        }
        float m  = s1 * (1.f/512.f);
        float rs = rsqrtf(s2 * (1.f/512.f) - m*m + 1e-3f);
        float* orow = out + (size_t)(rowb + r) * 512;
        #pragma unroll
        for (int j = 0; j < 8; ++j)
            orow[tx + 64*j] = fmaf(gv[j], (v[j]-m)*rs, bbv[j]);
    }
}

extern "C" void kernel_launch(void* const* d_in, const int* in_sizes, int n_in,
                              void* d_out, int out_size, void* d_ws, size_t ws_size,
                              hipStream_t stream)
{
    const float* inp  = (const float*)d_in[0];
    const float* wq   = (const float*)d_in[1];
    const float* bq   = (const float*)d_in[2];
    const float* wk   = (const float*)d_in[3];
    const float* bk   = (const float*)d_in[4];
    const float* wv   = (const float*)d_in[5];
    const float* bv   = (const float*)d_in[6];
    const float* relk = (const float*)d_in[7];
    const float* relv = (const float*)d_in[8];
    const float* ga   = (const float*)d_in[9];
    const float* ba   = (const float*)d_in[10];
    const float* w1   = (const float*)d_in[11];
    const float* b1   = (const float*)d_in[12];
    const float* w2   = (const float*)d_in[13];
    const float* b2   = (const float*)d_in[14];
    const float* gf   = (const float*)d_in[15];
    const float* bf   = (const float*)d_in[16];
    const float* wd   = (const float*)d_in[17];
    const float* bd   = (const float*)d_in[18];
    const float* go_  = (const float*)d_in[19];
    const float* bo_  = (const float*)d_in[20];

    float* ws = (float*)d_ws;
    float* pe = ws;             // 504 floats (transposed [f][s])
    float* ff = ws + 512;       // N*504 floats
    const int N = in_sizes[0] / 504;   // 32768

    hipLaunchKernelGGL(posenc_kernel, dim3(1), dim3(512), 0, stream, pe);
    hipLaunchKernelGGL(token_kernel, dim3((N + 11) / 12), dim3(256), 0, stream,
                       inp, wq, bq, wk, bk, wv, bv, relk, relv, ga, ba,
                       w1, b1, w2, b2, gf, bf, pe, ff, N);
    hipLaunchKernelGGL(dense_ln_kernel, dim3(N/32), dim3(256), 0, stream,
                       ff, wd, bd, go_, bo_, (float*)d_out);
}

// Round 5
// 2986.225 us; speedup vs baseline: 2.6251x; 2.6251x over previous
//
#include <hip/hip_runtime.h>
#include <math.h>

// ---------------- LDS layout for token kernel (floats) ----------------
#define O_WQ   0
#define O_WK   576
#define O_WV   1152
#define O_RELK 1728
#define O_RELV 1836
#define O_W1   1944
#define O_W2   4248
#define O_BQ   6552
#define O_BK   6576
#define O_BV   6600
#define O_B1   6624
#define O_B2   6720
#define O_GA   6744
#define O_BA   6768
#define O_GF   6792
#define O_BF   6816
#define O_PE   6840                 // 504, transposed [f][s]
#define O_KV   7344                 // [12 tokens][504]: raw input -> k -> v -> ff out
#define SM_TOT (O_KV + 12*504)      // 13392 floats = 53568 B -> 3 blocks/CU

// ---------------- kernel 0: positional encoding table (transposed [f][s]) ----------------
__global__ void posenc_kernel(float* __restrict__ pe) {
    int i = threadIdx.x;
    if (i < 504) {
        int f = i / 21, s = i % 21;
        double e = (double)(2 * (f / 2)) / 24.0;
        double ang = (double)s / pow(10000.0, e);
        float v = (f & 1) ? cosf((float)ang) : sinf((float)ang);
        pe[i] = 0.01f * v + 0.01f;   // folded *0.01 + 0.01
    }
}

// ---------------- kernel 1: fused per-token transformer, one row per lane ----------------
// All private arrays are accessed ONLY with compile-time-constant indices
// (fully unrolled loops, no pointer selection) -> no scratch.
__global__ __launch_bounds__(256, 3) void token_kernel(
    const float* __restrict__ inp,
    const float* __restrict__ wq, const float* __restrict__ bq,
    const float* __restrict__ wk, const float* __restrict__ bk,
    const float* __restrict__ wv, const float* __restrict__ bv,
    const float* __restrict__ relk, const float* __restrict__ relv,
    const float* __restrict__ ga, const float* __restrict__ ba,
    const float* __restrict__ w1, const float* __restrict__ b1,
    const float* __restrict__ w2, const float* __restrict__ b2,
    const float* __restrict__ gf, const float* __restrict__ bf,
    const float* __restrict__ pe, float* __restrict__ ffout, int ntok)
{
    __shared__ __align__(16) float sm[SM_TOT];
    const int tid  = threadIdx.x;
    const int lane = tid & 63;
    const int wv_  = tid >> 6;

    // ---- coalesced input staging: wave's 3 tokens (1512 floats) -> LDS tile ----
    {
        const size_t lim4  = (size_t)ntok * 126;
        const size_t base4 = ((size_t)blockIdx.x * 12 + wv_ * 3) * 126;
        const float4* in4 = (const float4*)inp;
        float4* t4 = (float4*)&sm[O_KV + wv_ * 1512];
        #pragma unroll
        for (int c = 0; c < 6; ++c) {
            int idx = lane + c * 64;
            if (idx < 378) {
                float4 v4 = make_float4(0.f, 0.f, 0.f, 0.f);
                if (base4 + idx < lim4) v4 = in4[base4 + idx];
                t4[idx] = v4;
            }
        }
    }

    // ---- cooperative weight staging ----
    for (int i = tid; i < 576; i += 256) { sm[O_WQ+i]=wq[i]; sm[O_WK+i]=wk[i]; sm[O_WV+i]=wv[i]; }
    for (int i = tid; i < 2304; i += 256) { sm[O_W1+i]=w1[i]; sm[O_W2+i]=w2[i]; }
    if (tid < 108) { sm[O_RELK+tid]=relk[tid]; sm[O_RELV+tid]=relv[tid]; }
    if (tid < 24) { sm[O_BQ+tid]=bq[tid]; sm[O_BK+tid]=bk[tid]; sm[O_BV+tid]=bv[tid];
                    sm[O_B2+tid]=b2[tid]; sm[O_GA+tid]=ga[tid]; sm[O_BA+tid]=ba[tid];
                    sm[O_GF+tid]=gf[tid]; sm[O_BF+tid]=bf[tid]; }
    if (tid >= 128 && tid < 224) sm[O_B1+tid-128] = b1[tid-128];
    for (int i = tid; i < 504; i += 256) sm[O_PE+i] = pe[i];
    __syncthreads();

    // ---- lane -> (token t, row s) ----
    int t = lane / 21;
    int s = lane - t * 21;
    if (lane == 63) { t = 2; s = 20; }     // dummy lane mirrors lane 62 (benign dup writes)
    float* tile  = &sm[O_KV + (wv_*3 + t) * 504];
    float* myrow = tile + s * 24;

    // ---- x row from LDS (transposed) + posenc ----
    float x[24];
    #pragma unroll
    for (int f = 0; f < 24; ++f)
        x[f] = tile[f*21 + s] + sm[O_PE + f*21 + s];

    // ---- k = relu(x@Wk+bk) -> LDS (overwrites raw input; all x reads issued before) ----
    #pragma unroll
    for (int fc = 0; fc < 24; fc += 4) {
        float4 b4 = *(const float4*)&sm[O_BK + fc];
        float a0=b4.x, a1=b4.y, a2=b4.z, a3=b4.w;
        #pragma unroll
        for (int j = 0; j < 24; ++j) {
            float4 w4 = *(const float4*)&sm[O_WK + j*24 + fc];
            a0 = fmaf(x[j], w4.x, a0); a1 = fmaf(x[j], w4.y, a1);
            a2 = fmaf(x[j], w4.z, a2); a3 = fmaf(x[j], w4.w, a3);
        }
        *(float4*)(myrow + fc) = make_float4(fmaxf(a0,0.f), fmaxf(a1,0.f), fmaxf(a2,0.f), fmaxf(a3,0.f));
    }

    // ---- q = relu(x@Wq+bq) -> regs (k-write latency hides under this) ----
    float q[24];
    #pragma unroll
    for (int fc = 0; fc < 24; fc += 4) {
        float4 b4 = *(const float4*)&sm[O_BQ + fc];
        float a0=b4.x, a1=b4.y, a2=b4.z, a3=b4.w;
        #pragma unroll
        for (int j = 0; j < 24; ++j) {
            float4 w4 = *(const float4*)&sm[O_WQ + j*24 + fc];
            a0 = fmaf(x[j], w4.x, a0); a1 = fmaf(x[j], w4.y, a1);
            a2 = fmaf(x[j], w4.z, a2); a3 = fmaf(x[j], w4.w, a3);
        }
        q[fc]=fmaxf(a0,0.f); q[fc+1]=fmaxf(a1,0.f); q[fc+2]=fmaxf(a2,0.f); q[fc+3]=fmaxf(a3,0.f);
    }
    asm volatile("s_waitcnt lgkmcnt(0)" ::: "memory");   // wave's k writes visible

    // ---- logits (both heads share rel_k row) + softmax, fully in-register ----
    const float rsc = 0.28867513459481287f;   // 1/sqrt(12)
    float lg0[21], lg1[21];
    #pragma unroll
    for (int ks = 0; ks < 21; ++ks) {
        int dd = ks - s; dd = dd < -4 ? -4 : (dd > 4 ? 4 : dd); dd += 4;
        const float* kr = tile + ks*24;
        const float* rk = &sm[O_RELK + dd*12];
        float a0 = 0.f, a1 = 0.f;
        #pragma unroll
        for (int c = 0; c < 3; ++c) {
            float4 r4 = *(const float4*)(rk + c*4);
            float4 k4 = *(const float4*)(kr + c*4);
            float4 k5 = *(const float4*)(kr + 12 + c*4);
            a0 = fmaf(q[c*4+0],    k4.x + r4.x, a0);
            a0 = fmaf(q[c*4+1],    k4.y + r4.y, a0);
            a0 = fmaf(q[c*4+2],    k4.z + r4.z, a0);
            a0 = fmaf(q[c*4+3],    k4.w + r4.w, a0);
            a1 = fmaf(q[12+c*4+0], k5.x + r4.x, a1);
            a1 = fmaf(q[12+c*4+1], k5.y + r4.y, a1);
            a1 = fmaf(q[12+c*4+2], k5.z + r4.z, a1);
            a1 = fmaf(q[12+c*4+3], k5.w + r4.w, a1);
        }
        lg0[ks] = a0 * rsc; lg1[ks] = a1 * rsc;
    }
    {
        float m0 = lg0[0], m1 = lg1[0];
        #pragma unroll
        for (int ks = 1; ks < 21; ++ks) { m0 = fmaxf(m0, lg0[ks]); m1 = fmaxf(m1, lg1[ks]); }
        float s0 = 0.f, s1 = 0.f;
        #pragma unroll
        for (int ks = 0; ks < 21; ++ks) {
            float e0 = __expf(lg0[ks]-m0); lg0[ks] = e0; s0 += e0;
            float e1 = __expf(lg1[ks]-m1); lg1[ks] = e1; s1 += e1;
        }
        float i0 = 1.f/s0, i1 = 1.f/s1;
        #pragma unroll
        for (int ks = 0; ks < 21; ++ks) { lg0[ks] *= i0; lg1[ks] *= i1; }
    }

    // ---- v = relu(x@Wv+bv) -> LDS (k reads all retired by now; in-order DS + waitcnt) ----
    asm volatile("s_waitcnt lgkmcnt(0)" ::: "memory");
    #pragma unroll
    for (int fc = 0; fc < 24; fc += 4) {
        float4 b4 = *(const float4*)&sm[O_BV + fc];
        float a0=b4.x, a1=b4.y, a2=b4.z, a3=b4.w;
        #pragma unroll
        for (int j = 0; j < 24; ++j) {
            float4 w4 = *(const float4*)&sm[O_WV + j*24 + fc];
            a0 = fmaf(x[j], w4.x, a0); a1 = fmaf(x[j], w4.y, a1);
            a2 = fmaf(x[j], w4.z, a2); a3 = fmaf(x[j], w4.w, a3);
        }
        *(float4*)(myrow + fc) = make_float4(fmaxf(a0,0.f), fmaxf(a1,0.f), fmaxf(a2,0.f), fmaxf(a3,0.f));
    }
    asm volatile("s_waitcnt lgkmcnt(0)" ::: "memory");

    // ---- o = p · (v + rel_v) ----
    float o[24];
    #pragma unroll
    for (int f = 0; f < 24; ++f) o[f] = 0.f;
    #pragma unroll
    for (int ks = 0; ks < 21; ++ks) {
        int dd = ks - s; dd = dd < -4 ? -4 : (dd > 4 ? 4 : dd); dd += 4;
        const float* vr = tile + ks*24;
        const float* rv = &sm[O_RELV + dd*12];
        float w0 = lg0[ks], w1v = lg1[ks];
        #pragma unroll
        for (int c = 0; c < 3; ++c) {
            float4 r4 = *(const float4*)(rv + c*4);
            float4 v4 = *(const float4*)(vr + c*4);
            float4 v5 = *(const float4*)(vr + 12 + c*4);
            o[c*4+0]    = fmaf(w0,  v4.x + r4.x, o[c*4+0]);
            o[c*4+1]    = fmaf(w0,  v4.y + r4.y, o[c*4+1]);
            o[c*4+2]    = fmaf(w0,  v4.z + r4.z, o[c*4+2]);
            o[c*4+3]    = fmaf(w0,  v4.w + r4.w, o[c*4+3]);
            o[12+c*4+0] = fmaf(w1v, v5.x + r4.x, o[12+c*4+0]);
            o[12+c*4+1] = fmaf(w1v, v5.y + r4.y, o[12+c*4+1]);
            o[12+c*4+2] = fmaf(w1v, v5.z + r4.z, o[12+c*4+2]);
            o[12+c*4+3] = fmaf(w1v, v5.w + r4.w, o[12+c*4+3]);
        }
    }

    // ---- attn = LN(o + x), lane-local ----
    float at[24];
    {
        float s1 = 0.f, s2 = 0.f;
        #pragma unroll
        for (int f = 0; f < 24; ++f) { at[f] = o[f] + x[f]; s1 += at[f]; s2 = fmaf(at[f], at[f], s2); }
        float m = s1 * (1.f/24.f);
        float rs = rsqrtf(s2*(1.f/24.f) - m*m + 1e-3f);
        #pragma unroll
        for (int f = 0; f < 24; ++f) at[f] = fmaf(sm[O_GA+f], (at[f]-m)*rs, sm[O_BA+f]);
    }

    // ---- ff = LN( relu(at@w1+b1)@w2 + b2 + at ), hidden in 24-wide chunks ----
    float ffa[24];
    #pragma unroll
    for (int fc = 0; fc < 24; fc += 4) {
        float4 b4 = *(const float4*)&sm[O_B2 + fc];
        ffa[fc]=b4.x; ffa[fc+1]=b4.y; ffa[fc+2]=b4.z; ffa[fc+3]=b4.w;
    }
    #pragma unroll
    for (int cc = 0; cc < 96; cc += 24) {
        float hid[24];
        #pragma unroll
        for (int lcx = 0; lcx < 24; lcx += 4) {
            float4 b4 = *(const float4*)&sm[O_B1 + cc + lcx];
            hid[lcx]=b4.x; hid[lcx+1]=b4.y; hid[lcx+2]=b4.z; hid[lcx+3]=b4.w;
        }
        #pragma unroll
        for (int j = 0; j < 24; ++j) {
            float xv = at[j];
            #pragma unroll
            for (int lcx = 0; lcx < 24; lcx += 4) {
                float4 w4 = *(const float4*)&sm[O_W1 + j*96 + cc + lcx];
                hid[lcx]   = fmaf(xv, w4.x, hid[lcx]);
                hid[lcx+1] = fmaf(xv, w4.y, hid[lcx+1]);
                hid[lcx+2] = fmaf(xv, w4.z, hid[lcx+2]);
                hid[lcx+3] = fmaf(xv, w4.w, hid[lcx+3]);
            }
        }
        #pragma unroll
        for (int lcx = 0; lcx < 24; ++lcx) hid[lcx] = fmaxf(hid[lcx], 0.f);
        #pragma unroll
        for (int lcx = 0; lcx < 24; ++lcx) {
            float hv = hid[lcx];
            #pragma unroll
            for (int f = 0; f < 24; f += 4) {
                float4 w4 = *(const float4*)&sm[O_W2 + (cc+lcx)*24 + f];
                ffa[f]   = fmaf(hv, w4.x, ffa[f]);
                ffa[f+1] = fmaf(hv, w4.y, ffa[f+1]);
                ffa[f+2] = fmaf(hv, w4.z, ffa[f+2]);
                ffa[f+3] = fmaf(hv, w4.w, ffa[f+3]);
            }
        }
    }
    {
        float s1 = 0.f, s2 = 0.f;
        #pragma unroll
        for (int f = 0; f < 24; ++f) { ffa[f] += at[f]; s1 += ffa[f]; s2 = fmaf(ffa[f], ffa[f], s2); }
        float m = s1 * (1.f/24.f);
        float rs = rsqrtf(s2*(1.f/24.f) - m*m + 1e-3f);
        #pragma unroll
        for (int f = 0; f < 24; ++f) ffa[f] = fmaf(sm[O_GF+f], (ffa[f]-m)*rs, sm[O_BF+f]);
    }

    // ---- transpose via tile (v reads all retired), then coalesced store ----
    #pragma unroll
    for (int f = 0; f < 24; ++f) tile[f*21 + s] = ffa[f];
    asm volatile("s_waitcnt lgkmcnt(0)" ::: "memory");
    {
        const size_t lim4  = (size_t)ntok * 126;
        const size_t base4 = ((size_t)blockIdx.x * 12 + wv_ * 3) * 126;
        float4* out4 = (float4*)ffout;
        const float4* t4 = (const float4*)&sm[O_KV + wv_ * 1512];
        #pragma unroll
        for (int c = 0; c < 6; ++c) {
            int idx = lane + c * 64;
            if (idx < 378 && base4 + idx < lim4)
                out4[base4 + idx] = t4[idx];
        }
    }
}

// ---------------- kernel 2: [N,504]@[504,512] + bias + relu (LN done separately) ----------------
// Block: 64 rows x 512 cols, 4 waves (wave w owns cols [w*128, w*128+128)).
// Lane (lr=l/8, lc=l%8): thread tile 8 rows x 16 cols. B reads are 8-address
// broadcast b128 -> conflict-free; A reads 2-way (free).
#define DB_LDA 68
__global__ __launch_bounds__(256, 2) void dense_kernel(
    const float* __restrict__ A, const float* __restrict__ wd,
    const float* __restrict__ bd, float* __restrict__ out)
{
    __shared__ __align__(16) float At[24*DB_LDA];   // 1632 floats
    __shared__ __align__(16) float Bs[24*512];      // 12288 floats
    const int tid  = threadIdx.x;
    const int w    = tid >> 6;
    const int lane = tid & 63;
    const int lr   = lane >> 3;
    const int lc   = lane & 7;
    const int row0 = blockIdx.x * 64;
    const int colb = w*128 + lc*4;   // + cb*32

    float acc[8][16];
    #pragma unroll
    for (int r = 0; r < 8; ++r)
        #pragma unroll
        for (int j = 0; j < 16; ++j) acc[r][j] = 0.f;

    for (int k0 = 0; k0 < 504; k0 += 24) {
        __syncthreads();
        #pragma unroll
        for (int i = 0; i < 6; ++i) {
            int ii = tid + i*256;                 // 1536 = 64 rows x 24 kk
            int r = ii / 24, kk = ii - r*24;
            At[kk*DB_LDA + r] = A[(size_t)(row0 + r)*504 + k0 + kk];
        }
        const float4* Bg = (const float4*)(wd + k0*512);
        float4* Bs4 = (float4*)Bs;
        #pragma unroll
        for (int i = 0; i < 12; ++i) Bs4[tid + i*256] = Bg[tid + i*256];
        __syncthreads();

        #pragma unroll 4
        for (int kk = 0; kk < 24; ++kk) {
            float4 a0 = *(const float4*)&At[kk*DB_LDA + lr*8];
            float4 a1 = *(const float4*)&At[kk*DB_LDA + lr*8 + 4];
            float av[8] = {a0.x,a0.y,a0.z,a0.w,a1.x,a1.y,a1.z,a1.w};
            float bv[16];
            #pragma unroll
            for (int cb = 0; cb < 4; ++cb) {
                float4 b4 = *(const float4*)&Bs[kk*512 + colb + cb*32];
                bv[cb*4+0]=b4.x; bv[cb*4+1]=b4.y; bv[cb*4+2]=b4.z; bv[cb*4+3]=b4.w;
            }
            #pragma unroll
            for (int r = 0; r < 8; ++r)
                #pragma unroll
                for (int j = 0; j < 16; ++j)
                    acc[r][j] = fmaf(av[r], bv[j], acc[r][j]);
        }
    }

    float4 bias[4];
    #pragma unroll
    for (int cb = 0; cb < 4; ++cb) bias[cb] = *(const float4*)&bd[colb + cb*32];
    #pragma unroll
    for (int r = 0; r < 8; ++r) {
        float* orow = out + (size_t)(row0 + lr*8 + r)*512;
        #pragma unroll
        for (int cb = 0; cb < 4; ++cb) {
            float4 o4;
            o4.x = fmaxf(acc[r][cb*4+0] + bias[cb].x, 0.f);
            o4.y = fmaxf(acc[r][cb*4+1] + bias[cb].y, 0.f);
            o4.z = fmaxf(acc[r][cb*4+2] + bias[cb].z, 0.f);
            o4.w = fmaxf(acc[r][cb*4+3] + bias[cb].w, 0.f);
            *(float4*)&orow[colb + cb*32] = o4;
        }
    }
}

// ---------------- kernel 3: in-place LN over 512 cols, one row per wave ----------------
__global__ __launch_bounds__(256, 4) void ln512_kernel(
    float* __restrict__ out, const float* __restrict__ g, const float* __restrict__ b)
{
    const int lane = threadIdx.x & 63;
    const size_t row = (size_t)blockIdx.x * 4 + (threadIdx.x >> 6);
    float4* p = (float4*)(out + row*512) + lane*2;
    float4 v0 = p[0], v1 = p[1];
    float s1 = v0.x+v0.y+v0.z+v0.w + v1.x+v1.y+v1.z+v1.w;
    float s2 = 0.f;
    s2 = fmaf(v0.x,v0.x,s2); s2 = fmaf(v0.y,v0.y,s2); s2 = fmaf(v0.z,v0.z,s2); s2 = fmaf(v0.w,v0.w,s2);
    s2 = fmaf(v1.x,v1.x,s2); s2 = fmaf(v1.y,v1.y,s2); s2 = fmaf(v1.z,v1.z,s2); s2 = fmaf(v1.w,v1.w,s2);
    #pragma unroll
    for (int off = 32; off > 0; off >>= 1) {
        s1 += __shfl_xor(s1, off);
        s2 += __shfl_xor(s2, off);
    }
    float m  = s1 * (1.f/512.f);
    float rs = rsqrtf(s2 * (1.f/512.f) - m*m + 1e-3f);
    const float4* g4 = (const float4*)g + lane*2;
    const float4* b4 = (const float4*)b + lane*2;
    float4 ga0 = g4[0], ga1 = g4[1], bb0 = b4[0], bb1 = b4[1];
    v0.x = fmaf(ga0.x, (v0.x-m)*rs, bb0.x);
    v0.y = fmaf(ga0.y, (v0.y-m)*rs, bb0.y);
    v0.z = fmaf(ga0.z, (v0.z-m)*rs, bb0.z);
    v0.w = fmaf(ga0.w, (v0.w-m)*rs, bb0.w);
    v1.x = fmaf(ga1.x, (v1.x-m)*rs, bb1.x);
    v1.y = fmaf(ga1.y, (v1.y-m)*rs, bb1.y);
    v1.z = fmaf(ga1.z, (v1.z-m)*rs, bb1.z);
    v1.w = fmaf(ga1.w, (v1.w-m)*rs, bb1.w);
    p[0] = v0; p[1] = v1;
}

extern "C" void kernel_launch(void* const* d_in, const int* in_sizes, int n_in,
                              void* d_out, int out_size, void* d_ws, size_t ws_size,
                              hipStream_t stream)
{
    const float* inp  = (const float*)d_in[0];
    const float* wq   = (const float*)d_in[1];
    const float* bq   = (const float*)d_in[2];
    const float* wk   = (const float*)d_in[3];
    const float* bk   = (const float*)d_in[4];
    const float* wv   = (const float*)d_in[5];
    const float* bv   = (const float*)d_in[6];
    const float* relk = (const float*)d_in[7];
    const float* relv = (const float*)d_in[8];
    const float* ga   = (const float*)d_in[9];
    const float* ba   = (const float*)d_in[10];
    const float* w1   = (const float*)d_in[11];
    const float* b1   = (const float*)d_in[12];
    const float* w2   = (const float*)d_in[13];
    const float* b2   = (const float*)d_in[14];
    const float* gf   = (const float*)d_in[15];
    const float* bf   = (const float*)d_in[16];
    const float* wd   = (const float*)d_in[17];
    const float* bd   = (const float*)d_in[18];
    const float* go_  = (const float*)d_in[19];
    const float* bo_  = (const float*)d_in[20];

    float* ws = (float*)d_ws;
    float* pe = ws;             // 504 floats (transposed [f][s])
    float* ff = ws + 512;       // N*504 floats
    const int N = in_sizes[0] / 504;   // 32768

    hipLaunchKernelGGL(posenc_kernel, dim3(1), dim3(512), 0, stream, pe);
    hipLaunchKernelGGL(token_kernel, dim3((N + 11) / 12), dim3(256), 0, stream,
                       inp, wq, bq, wk, bk, wv, bv, relk, relv, ga, ba,
                       w1, b1, w2, b2, gf, bf, pe, ff, N);
    hipLaunchKernelGGL(dense_kernel, dim3(N/64), dim3(256), 0, stream,
                       ff, wd, bd, (float*)d_out);
    hipLaunchKernelGGL(ln512_kernel, dim3(N/4), dim3(256), 0, stream,
                       (float*)d_out, go_, bo_);
}

// Round 7
// 808.365 us; speedup vs baseline: 9.6977x; 3.6942x over previous
//
#include <hip/hip_runtime.h>
#include <math.h>

// ---------------- LDS layout for token kernel (floats) ----------------
#define O_WQ   0
#define O_WK   576
#define O_WV   1152
#define O_RELK 1728
#define O_RELV 1836
#define O_W1   1944
#define O_W2   4248
#define O_BQ   6552
#define O_BK   6576
#define O_BV   6600
#define O_B1   6624
#define O_B2   6720
#define O_GA   6744
#define O_BA   6768
#define O_GF   6792
#define O_BF   6816
#define O_PE   6840                 // 504, transposed [f][s]
#define O_KV   7344                 // [12 tokens][504]: raw input -> k -> v -> ff out
#define SM_TOT (O_KV + 12*504)      // 13392 floats = 53568 B -> 3 blocks/CU

// ---------------- repetition macros (all private state = named scalars) ----------------
#define REP21(M) M(0) M(1) M(2) M(3) M(4) M(5) M(6) M(7) M(8) M(9) M(10) \
                 M(11) M(12) M(13) M(14) M(15) M(16) M(17) M(18) M(19) M(20)
#define REP24(M) REP21(M) M(21) M(22) M(23)

// load 6 float4 (24 floats) from LDS pointer
#define LD6(bp,A,B,C,D,E,F) \
  const float* Lb_ = (bp); \
  float4 A=*(const float4*)(Lb_+0),  B=*(const float4*)(Lb_+4),  C=*(const float4*)(Lb_+8), \
         D=*(const float4*)(Lb_+12), E=*(const float4*)(Lb_+16), F=*(const float4*)(Lb_+20);

// 24 fma: P##i += xs * {A..F}[i]
#define FMA24(P,xs,A,B,C,D,E,F) \
  P##0 =fmaf(xs,A.x,P##0 ); P##1 =fmaf(xs,A.y,P##1 ); P##2 =fmaf(xs,A.z,P##2 ); P##3 =fmaf(xs,A.w,P##3 ); \
  P##4 =fmaf(xs,B.x,P##4 ); P##5 =fmaf(xs,B.y,P##5 ); P##6 =fmaf(xs,B.z,P##6 ); P##7 =fmaf(xs,B.w,P##7 ); \
  P##8 =fmaf(xs,C.x,P##8 ); P##9 =fmaf(xs,C.y,P##9 ); P##10=fmaf(xs,C.z,P##10); P##11=fmaf(xs,C.w,P##11); \
  P##12=fmaf(xs,D.x,P##12); P##13=fmaf(xs,D.y,P##13); P##14=fmaf(xs,D.z,P##14); P##15=fmaf(xs,D.w,P##15); \
  P##16=fmaf(xs,E.x,P##16); P##17=fmaf(xs,E.y,P##17); P##18=fmaf(xs,E.z,P##18); P##19=fmaf(xs,E.w,P##19); \
  P##20=fmaf(xs,F.x,P##20); P##21=fmaf(xs,F.y,P##21); P##22=fmaf(xs,F.z,P##22); P##23=fmaf(xs,F.w,P##23);

// one W-row update: P##0..23 += x##j * W[j][0..23]
#define WJ(j,W,P) { const float xj_ = x##j; LD6(&sm[(W)+(j)*24], wA,wB,wC,wD,wE,wF) \
                    FMA24(P,xj_,wA,wB,wC,wD,wE,wF) }
#define REPW24(W,P) WJ(0,W,P) WJ(1,W,P) WJ(2,W,P) WJ(3,W,P) WJ(4,W,P) WJ(5,W,P) \
  WJ(6,W,P) WJ(7,W,P) WJ(8,W,P) WJ(9,W,P) WJ(10,W,P) WJ(11,W,P) WJ(12,W,P) WJ(13,W,P) \
  WJ(14,W,P) WJ(15,W,P) WJ(16,W,P) WJ(17,W,P) WJ(18,W,P) WJ(19,W,P) WJ(20,W,P) \
  WJ(21,W,P) WJ(22,W,P) WJ(23,W,P)

// ---------------- kernel 0: positional encoding table (transposed [f][s]) ----------------
__global__ void posenc_kernel(float* __restrict__ pe) {
    int i = threadIdx.x;
    if (i < 504) {
        int f = i / 21, s = i % 21;
        double e = (double)(2 * (f / 2)) / 24.0;
        double ang = (double)s / pow(10000.0, e);
        float v = (f & 1) ? cosf((float)ang) : sinf((float)ang);
        pe[i] = 0.01f * v + 0.01f;   // folded *0.01 + 0.01
    }
}

// ---------------- kernel 1: fused per-token transformer, one row per lane ----------------
// ALL per-lane state is named scalars (macro-expanded straight-line code):
// nothing for the compiler to demote to scratch regardless of unroll decisions.
__global__ __launch_bounds__(256, 3) void token_kernel(
    const float* __restrict__ inp,
    const float* __restrict__ wq, const float* __restrict__ bq,
    const float* __restrict__ wk, const float* __restrict__ bk,
    const float* __restrict__ wv, const float* __restrict__ bv,
    const float* __restrict__ relk, const float* __restrict__ relv,
    const float* __restrict__ ga, const float* __restrict__ ba,
    const float* __restrict__ w1, const float* __restrict__ b1,
    const float* __restrict__ w2, const float* __restrict__ b2,
    const float* __restrict__ gf, const float* __restrict__ bf,
    const float* __restrict__ pe, float* __restrict__ ffout, int ntok)
{
    __shared__ __align__(16) float sm[SM_TOT];
    const int tid  = threadIdx.x;
    const int lane = tid & 63;
    const int wv_  = tid >> 6;

    // ---- coalesced input staging: wave's 3 tokens (1512 floats) -> LDS tile ----
    {
        const size_t lim4  = (size_t)ntok * 126;
        const size_t base4 = ((size_t)blockIdx.x * 12 + wv_ * 3) * 126;
        const float4* in4 = (const float4*)inp;
        float4* t4 = (float4*)&sm[O_KV + wv_ * 1512];
        #pragma unroll
        for (int c = 0; c < 6; ++c) {
            int idx = lane + c * 64;
            if (idx < 378) {
                float4 v4 = make_float4(0.f, 0.f, 0.f, 0.f);
                if (base4 + idx < lim4) v4 = in4[base4 + idx];
                t4[idx] = v4;
            }
        }
    }

    // ---- cooperative weight staging ----
    for (int i = tid; i < 576; i += 256) { sm[O_WQ+i]=wq[i]; sm[O_WK+i]=wk[i]; sm[O_WV+i]=wv[i]; }
    for (int i = tid; i < 2304; i += 256) { sm[O_W1+i]=w1[i]; sm[O_W2+i]=w2[i]; }
    if (tid < 108) { sm[O_RELK+tid]=relk[tid]; sm[O_RELV+tid]=relv[tid]; }
    if (tid < 24) { sm[O_BQ+tid]=bq[tid]; sm[O_BK+tid]=bk[tid]; sm[O_BV+tid]=bv[tid];
                    sm[O_B2+tid]=b2[tid]; sm[O_GA+tid]=ga[tid]; sm[O_BA+tid]=ba[tid];
                    sm[O_GF+tid]=gf[tid]; sm[O_BF+tid]=bf[tid]; }
    if (tid >= 128 && tid < 224) sm[O_B1+tid-128] = b1[tid-128];
    for (int i = tid; i < 504; i += 256) sm[O_PE+i] = pe[i];
    __syncthreads();

    // ---- lane -> (token t, row s) ----
    int t = lane / 21;
    int s = lane - t * 21;
    if (lane == 63) { t = 2; s = 20; }     // dummy lane mirrors lane 62 (benign dup writes)
    float* tile  = &sm[O_KV + (wv_*3 + t) * 504];
    float* myrow = tile + s * 24;

    // ---- x row from LDS (transposed) + posenc ----
#define DX(i) float x##i = tile[(i)*21 + s] + sm[O_PE + (i)*21 + s];
    REP24(DX)

    // ---- k = relu(x@Wk+bk) -> LDS (overwrites raw input; x already read) ----
    {
#define DKK(i) float kk##i = sm[O_BK+(i)];
        REP24(DKK)
        REPW24(O_WK, kk)
        *(float4*)(myrow+ 0) = make_float4(fmaxf(kk0 ,0.f),fmaxf(kk1 ,0.f),fmaxf(kk2 ,0.f),fmaxf(kk3 ,0.f));
        *(float4*)(myrow+ 4) = make_float4(fmaxf(kk4 ,0.f),fmaxf(kk5 ,0.f),fmaxf(kk6 ,0.f),fmaxf(kk7 ,0.f));
        *(float4*)(myrow+ 8) = make_float4(fmaxf(kk8 ,0.f),fmaxf(kk9 ,0.f),fmaxf(kk10,0.f),fmaxf(kk11,0.f));
        *(float4*)(myrow+12) = make_float4(fmaxf(kk12,0.f),fmaxf(kk13,0.f),fmaxf(kk14,0.f),fmaxf(kk15,0.f));
        *(float4*)(myrow+16) = make_float4(fmaxf(kk16,0.f),fmaxf(kk17,0.f),fmaxf(kk18,0.f),fmaxf(kk19,0.f));
        *(float4*)(myrow+20) = make_float4(fmaxf(kk20,0.f),fmaxf(kk21,0.f),fmaxf(kk22,0.f),fmaxf(kk23,0.f));
    }

    // ---- q = relu(x@Wq+bq) -> named scalars (k-write latency hides under this) ----
#define DQQ(i) float q##i = sm[O_BQ+(i)];
    REP24(DQQ)
    REPW24(O_WQ, q)
#define RQ(i) q##i = fmaxf(q##i, 0.f);
    REP24(RQ)
    asm volatile("s_waitcnt lgkmcnt(0)" ::: "memory");   // wave's k writes visible

    // ---- logits (rel_k row shared by both heads) ----
#define DP_(i) float p0_##i, p1_##i;
    REP21(DP_)
#define LGT(ks) { \
    int dd=(ks)-s; dd=dd<-4?-4:(dd>4?4:dd); dd+=4; \
    const float* kr_ = tile + (ks)*24; \
    const float* rr_ = &sm[O_RELK + dd*12]; \
    LD6(kr_, kA,kB,kC,kD,kE,kF) \
    float4 rA=*(const float4*)(rr_+0), rB=*(const float4*)(rr_+4), rC=*(const float4*)(rr_+8); \
    float a0_=0.f, a1_=0.f; \
    a0_=fmaf(q0 ,kA.x+rA.x,a0_); a0_=fmaf(q1 ,kA.y+rA.y,a0_); a0_=fmaf(q2 ,kA.z+rA.z,a0_); a0_=fmaf(q3 ,kA.w+rA.w,a0_); \
    a0_=fmaf(q4 ,kB.x+rB.x,a0_); a0_=fmaf(q5 ,kB.y+rB.y,a0_); a0_=fmaf(q6 ,kB.z+rB.z,a0_); a0_=fmaf(q7 ,kB.w+rB.w,a0_); \
    a0_=fmaf(q8 ,kC.x+rC.x,a0_); a0_=fmaf(q9 ,kC.y+rC.y,a0_); a0_=fmaf(q10,kC.z+rC.z,a0_); a0_=fmaf(q11,kC.w+rC.w,a0_); \
    a1_=fmaf(q12,kD.x+rA.x,a1_); a1_=fmaf(q13,kD.y+rA.y,a1_); a1_=fmaf(q14,kD.z+rA.z,a1_); a1_=fmaf(q15,kD.w+rA.w,a1_); \
    a1_=fmaf(q16,kE.x+rB.x,a1_); a1_=fmaf(q17,kE.y+rB.y,a1_); a1_=fmaf(q18,kE.z+rB.z,a1_); a1_=fmaf(q19,kE.w+rB.w,a1_); \
    a1_=fmaf(q20,kF.x+rC.x,a1_); a1_=fmaf(q21,kF.y+rC.y,a1_); a1_=fmaf(q22,kF.z+rC.z,a1_); a1_=fmaf(q23,kF.w+rC.w,a1_); \
    p0_##ks = a0_*0.28867513459481287f; p1_##ks = a1_*0.28867513459481287f; }
    REP21(LGT)

    // ---- softmax (straight-line, both heads) ----
    {
        float m0 = p0_0, m1 = p1_0;
#define MX(i) m0 = fmaxf(m0, p0_##i); m1 = fmaxf(m1, p1_##i);
        REP21(MX)
        float sum0 = 0.f, sum1 = 0.f;
#define EX(i) p0_##i = __expf(p0_##i - m0); sum0 += p0_##i; \
              p1_##i = __expf(p1_##i - m1); sum1 += p1_##i;
        REP21(EX)
        float is0 = 1.f/sum0, is1 = 1.f/sum1;
#define NM(i) p0_##i *= is0; p1_##i *= is1;
        REP21(NM)
    }

    // ---- v = relu(x@Wv+bv) -> LDS (k reads retired; in-order DS + waitcnt) ----
    asm volatile("s_waitcnt lgkmcnt(0)" ::: "memory");
    {
#define DVV(i) float vv##i = sm[O_BV+(i)];
        REP24(DVV)
        REPW24(O_WV, vv)
        *(float4*)(myrow+ 0) = make_float4(fmaxf(vv0 ,0.f),fmaxf(vv1 ,0.f),fmaxf(vv2 ,0.f),fmaxf(vv3 ,0.f));
        *(float4*)(myrow+ 4) = make_float4(fmaxf(vv4 ,0.f),fmaxf(vv5 ,0.f),fmaxf(vv6 ,0.f),fmaxf(vv7 ,0.f));
        *(float4*)(myrow+ 8) = make_float4(fmaxf(vv8 ,0.f),fmaxf(vv9 ,0.f),fmaxf(vv10,0.f),fmaxf(vv11,0.f));
        *(float4*)(myrow+12) = make_float4(fmaxf(vv12,0.f),fmaxf(vv13,0.f),fmaxf(vv14,0.f),fmaxf(vv15,0.f));
        *(float4*)(myrow+16) = make_float4(fmaxf(vv16,0.f),fmaxf(vv17,0.f),fmaxf(vv18,0.f),fmaxf(vv19,0.f));
        *(float4*)(myrow+20) = make_float4(fmaxf(vv20,0.f),fmaxf(vv21,0.f),fmaxf(vv22,0.f),fmaxf(vv23,0.f));
    }
    asm volatile("s_waitcnt lgkmcnt(0)" ::: "memory");

    // ---- o = p · (v + rel_v) ----
#define DO_(i) float o##i = 0.f;
    REP24(DO_)
#define OT(ks) { \
    int dd=(ks)-s; dd=dd<-4?-4:(dd>4?4:dd); dd+=4; \
    const float* vr_ = tile + (ks)*24; \
    const float* rr_ = &sm[O_RELV + dd*12]; \
    LD6(vr_, vA,vB,vC,vD,vE,vF) \
    float4 rA=*(const float4*)(rr_+0), rB=*(const float4*)(rr_+4), rC=*(const float4*)(rr_+8); \
    const float w0_ = p0_##ks, w1_ = p1_##ks; \
    o0 =fmaf(w0_,vA.x+rA.x,o0 ); o1 =fmaf(w0_,vA.y+rA.y,o1 ); o2 =fmaf(w0_,vA.z+rA.z,o2 ); o3 =fmaf(w0_,vA.w+rA.w,o3 ); \
    o4 =fmaf(w0_,vB.x+rB.x,o4 ); o5 =fmaf(w0_,vB.y+rB.y,o5 ); o6 =fmaf(w0_,vB.z+rB.z,o6 ); o7 =fmaf(w0_,vB.w+rB.w,o7 ); \
    o8 =fmaf(w0_,vC.x+rC.x,o8 ); o9 =fmaf(w0_,vC.y+rC.y,o9 ); o10=fmaf(w0_,vC.z+rC.z,o10); o11=fmaf(w0_,vC.w+rC.w,o11); \
    o12=fmaf(w1_,vD.x+rA.x,o12); o13=fmaf(w1_,vD.y+rA.y,o13); o14=fmaf(w1_,vD.z+rA.z,o14); o15=fmaf(w1_,vD.w+rA.w,o15); \
    o16=fmaf(w1_,vE.x+rB.x,o16); o17=fmaf(w1_,vE.y+rB.y,o17); o18=fmaf(w1_,vE.z+rB.z,o18); o19=fmaf(w1_,vE.w+rB.w,o19); \
    o20=fmaf(w1_,vF.x+rC.x,o20); o21=fmaf(w1_,vF.y+rC.y,o21); o22=fmaf(w1_,vF.z+rC.z,o22); o23=fmaf(w1_,vF.w+rC.w,o23); }
    REP21(OT)

    // ---- attn = LN(o + x), lane-local ----
#define ATD(i) float at##i = o##i + x##i;
    REP24(ATD)
    {
        float sA = 0.f, sB = 0.f;
#define ASUM(i) sA += at##i; sB = fmaf(at##i, at##i, sB);
        REP24(ASUM)
        float mn = sA * (1.f/24.f);
        float rstd = rsqrtf(sB*(1.f/24.f) - mn*mn + 1e-3f);
#define ALN(i) at##i = fmaf(sm[O_GA+(i)], (at##i - mn)*rstd, sm[O_BA+(i)]);
        REP24(ALN)
    }

    // ---- ff = relu(at@w1+b1)@w2 + b2, hidden in 24-wide chunks ----
#define DFF(i) float ff##i = sm[O_B2+(i)];
    REP24(DFF)
    for (int cc = 0; cc < 96; cc += 24) {
#define DH2(i) float h##i = sm[O_B1 + cc + (i)];
        REP24(DH2)
#define HJ(j) { const float aj_ = at##j; LD6(&sm[O_W1+(j)*96+cc], wA,wB,wC,wD,wE,wF) \
                FMA24(h,aj_,wA,wB,wC,wD,wE,wF) }
        REP24(HJ)
#define RH(i) h##i = fmaxf(h##i, 0.f);
        REP24(RH)
#define FL(l) { const float hl_ = h##l; LD6(&sm[O_W2+(cc+(l))*24], wA,wB,wC,wD,wE,wF) \
                FMA24(ff,hl_,wA,wB,wC,wD,wE,wF) }
        REP24(FL)
    }

    // ---- ff = LN(ff + at) ----
    {
#define FR(i) ff##i += at##i;
        REP24(FR)
        float sC = 0.f, sD = 0.f;
#define FSUM(i) sC += ff##i; sD = fmaf(ff##i, ff##i, sD);
        REP24(FSUM)
        float mn2 = sC * (1.f/24.f);
        float rstd2 = rsqrtf(sD*(1.f/24.f) - mn2*mn2 + 1e-3f);
#define FLN(i) ff##i = fmaf(sm[O_GF+(i)], (ff##i - mn2)*rstd2, sm[O_BF+(i)]);
        REP24(FLN)
    }

    // ---- transpose via tile (v reads all retired), then coalesced store ----
#define STF(i) tile[(i)*21 + s] = ff##i;
    REP24(STF)
    asm volatile("s_waitcnt lgkmcnt(0)" ::: "memory");
    {
        const size_t lim4  = (size_t)ntok * 126;
        const size_t base4 = ((size_t)blockIdx.x * 12 + wv_ * 3) * 126;
        float4* out4 = (float4*)ffout;
        const float4* t4 = (const float4*)&sm[O_KV + wv_ * 1512];
        #pragma unroll
        for (int c = 0; c < 6; ++c) {
            int idx = lane + c * 64;
            if (idx < 378 && base4 + idx < lim4)
                out4[base4 + idx] = t4[idx];
        }
    }
}

// ---------------- kernel 2: [N,504]@[504,512] + bias + relu (LN done separately) ----------------
#define DB_LDA 68
__global__ __launch_bounds__(256, 2) void dense_kernel(
    const float* __restrict__ A, const float* __restrict__ wd,
    const float* __restrict__ bd, float* __restrict__ out)
{
    __shared__ __align__(16) float At[24*DB_LDA];   // 1632 floats
    __shared__ __align__(16) float Bs[24*512];      // 12288 floats
    const int tid  = threadIdx.x;
    const int w    = tid >> 6;
    const int lane = tid & 63;
    const int lr   = lane >> 3;
    const int lc   = lane & 7;
    const int row0 = blockIdx.x * 64;
    const int colb = w*128 + lc*4;   // + cb*32

    float acc[8][16];
    #pragma unroll
    for (int r = 0; r < 8; ++r)
        #pragma unroll
        for (int j = 0; j < 16; ++j) acc[r][j] = 0.f;

    for (int k0 = 0; k0 < 504; k0 += 24) {
        __syncthreads();
        #pragma unroll
        for (int i = 0; i < 6; ++i) {
            int ii = tid + i*256;                 // 1536 = 64 rows x 24 kk
            int r = ii / 24, kk = ii - r*24;
            At[kk*DB_LDA + r] = A[(size_t)(row0 + r)*504 + k0 + kk];
        }
        const float4* Bg = (const float4*)(wd + k0*512);
        float4* Bs4 = (float4*)Bs;
        #pragma unroll
        for (int i = 0; i < 12; ++i) Bs4[tid + i*256] = Bg[tid + i*256];
        __syncthreads();

        #pragma unroll 4
        for (int kk = 0; kk < 24; ++kk) {
            float4 a0 = *(const float4*)&At[kk*DB_LDA + lr*8];
            float4 a1 = *(const float4*)&At[kk*DB_LDA + lr*8 + 4];
            float av[8] = {a0.x,a0.y,a0.z,a0.w,a1.x,a1.y,a1.z,a1.w};
            float bv[16];
            #pragma unroll
            for (int cb = 0; cb < 4; ++cb) {
                float4 b4 = *(const float4*)&Bs[kk*512 + colb + cb*32];
                bv[cb*4+0]=b4.x; bv[cb*4+1]=b4.y; bv[cb*4+2]=b4.z; bv[cb*4+3]=b4.w;
            }
            #pragma unroll
            for (int r = 0; r < 8; ++r)
                #pragma unroll
                for (int j = 0; j < 16; ++j)
                    acc[r][j] = fmaf(av[r], bv[j], acc[r][j]);
        }
    }

    float4 bias[4];
    #pragma unroll
    for (int cb = 0; cb < 4; ++cb) bias[cb] = *(const float4*)&bd[colb + cb*32];
    #pragma unroll
    for (int r = 0; r < 8; ++r) {
        float* orow = out + (size_t)(row0 + lr*8 + r)*512;
        #pragma unroll
        for (int cb = 0; cb < 4; ++cb) {
            float4 o4;
            o4.x = fmaxf(acc[r][cb*4+0] + bias[cb].x, 0.f);
            o4.y = fmaxf(acc[r][cb*4+1] + bias[cb].y, 0.f);
            o4.z = fmaxf(acc[r][cb*4+2] + bias[cb].z, 0.f);
            o4.w = fmaxf(acc[r][cb*4+3] + bias[cb].w, 0.f);
            *(float4*)&orow[colb + cb*32] = o4;
        }
    }
}

// ---------------- kernel 3: in-place LN over 512 cols, one row per wave ----------------
__global__ __launch_bounds__(256, 4) void ln512_kernel(
    float* __restrict__ out, const float* __restrict__ g, const float* __restrict__ b)
{
    const int lane = threadIdx.x & 63;
    const size_t row = (size_t)blockIdx.x * 4 + (threadIdx.x >> 6);
    float4* p = (float4*)(out + row*512) + lane*2;
    float4 v0 = p[0], v1 = p[1];
    float s1 = v0.x+v0.y+v0.z+v0.w + v1.x+v1.y+v1.z+v1.w;
    float s2 = 0.f;
    s2 = fmaf(v0.x,v0.x,s2); s2 = fmaf(v0.y,v0.y,s2); s2 = fmaf(v0.z,v0.z,s2); s2 = fmaf(v0.w,v0.w,s2);
    s2 = fmaf(v1.x,v1.x,s2); s2 = fmaf(v1.y,v1.y,s2); s2 = fmaf(v1.z,v1.z,s2); s2 = fmaf(v1.w,v1.w,s2);
    #pragma unroll
    for (int off = 32; off > 0; off >>= 1) {
        s1 += __shfl_xor(s1, off);
        s2 += __shfl_xor(s2, off);
    }
    float m  = s1 * (1.f/512.f);
    float rs = rsqrtf(s2 * (1.f/512.f) - m*m + 1e-3f);
    const float4* g4 = (const float4*)g + lane*2;
    const float4* b4 = (const float4*)b + lane*2;
    float4 ga0 = g4[0], ga1 = g4[1], bb0 = b4[0], bb1 = b4[1];
    v0.x = fmaf(ga0.x, (v0.x-m)*rs, bb0.x);
    v0.y = fmaf(ga0.y, (v0.y-m)*rs, bb0.y);
    v0.z = fmaf(ga0.z, (v0.z-m)*rs, bb0.z);
    v0.w = fmaf(ga0.w, (v0.w-m)*rs, bb0.w);
    v1.x = fmaf(ga1.x, (v1.x-m)*rs, bb1.x);
    v1.y = fmaf(ga1.y, (v1.y-m)*rs, bb1.y);
    v1.z = fmaf(ga1.z, (v1.z-m)*rs, bb1.z);
    v1.w = fmaf(ga1.w, (v1.w-m)*rs, bb1.w);
    p[0] = v0; p[1] = v1;
}

extern "C" void kernel_launch(void* const* d_in, const int* in_sizes, int n_in,
                              void* d_out, int out_size, void* d_ws, size_t ws_size,
                              hipStream_t stream)
{
    const float* inp  = (const float*)d_in[0];
    const float* wq   = (const float*)d_in[1];
    const float* bq   = (const float*)d_in[2];
    const float* wk   = (const float*)d_in[3];
    const float* bk   = (const float*)d_in[4];
    const float* wv   = (const float*)d_in[5];
    const float* bv   = (const float*)d_in[6];
    const float* relk = (const float*)d_in[7];
    const float* relv = (const float*)d_in[8];
    const float* ga   = (const float*)d_in[9];
    const float* ba   = (const float*)d_in[10];
    const float* w1   = (const float*)d_in[11];
    const float* b1   = (const float*)d_in[12];
    const float* w2   = (const float*)d_in[13];
    const float* b2   = (const float*)d_in[14];
    const float* gf   = (const float*)d_in[15];
    const float* bf   = (const float*)d_in[16];
    const float* wd   = (const float*)d_in[17];
    const float* bd   = (const float*)d_in[18];
    const float* go_  = (const float*)d_in[19];
    const float* bo_  = (const float*)d_in[20];

    float* ws = (float*)d_ws;
    float* pe = ws;             // 504 floats (transposed [f][s])
    float* ff = ws + 512;       // N*504 floats
    const int N = in_sizes[0] / 504;   // 32768

    hipLaunchKernelGGL(posenc_kernel, dim3(1), dim3(512), 0, stream, pe);
    hipLaunchKernelGGL(token_kernel, dim3((N + 11) / 12), dim3(256), 0, stream,
                       inp, wq, bq, wk, bk, wv, bv, relk, relv, ga, ba,
                       w1, b1, w2, b2, gf, bf, pe, ff, N);
    hipLaunchKernelGGL(dense_kernel, dim3(N/64), dim3(256), 0, stream,
                       ff, wd, bd, (float*)d_out);
    hipLaunchKernelGGL(ln512_kernel, dim3(N/4), dim3(256), 0, stream,
                       (float*)d_out, go_, bo_);
}

// Round 8
// 802.863 us; speedup vs baseline: 9.7641x; 1.0069x over previous
//
#include <hip/hip_runtime.h>
#include <math.h>

// ---------------- LDS layout for token kernel (floats) ----------------
#define O_WQ   0
#define O_WK   576
#define O_WV   1152
#define O_RELK 1728
#define O_RELV 1836
#define O_W1   1944
#define O_W2   4248
#define O_BQ   6552
#define O_BK   6576
#define O_BV   6600
#define O_B1   6624
#define O_B2   6720
#define O_GA   6744
#define O_BA   6768
#define O_GF   6792
#define O_BF   6816
#define O_PE   6840                 // 504, transposed [f][s]
#define O_KV   7344                 // [12 tokens][504]: raw input -> k -> v -> ff out
#define SM_TOT (O_KV + 12*504)      // 13392 floats = 53568 B -> 3 blocks/CU (LDS-bound)

// ---------------- repetition macros (all private state = named scalars) ----------------
#define REP21(M) M(0) M(1) M(2) M(3) M(4) M(5) M(6) M(7) M(8) M(9) M(10) \
                 M(11) M(12) M(13) M(14) M(15) M(16) M(17) M(18) M(19) M(20)
#define REP24(M) REP21(M) M(21) M(22) M(23)

// load 6 float4 (24 floats) from LDS pointer
#define LD6(bp,A,B,C,D,E,F) \
  const float* Lb_ = (bp); \
  float4 A=*(const float4*)(Lb_+0),  B=*(const float4*)(Lb_+4),  C=*(const float4*)(Lb_+8), \
         D=*(const float4*)(Lb_+12), E=*(const float4*)(Lb_+16), F=*(const float4*)(Lb_+20);

// 24 fma: P##i += xs * {A..F}[i]
#define FMA24(P,xs,A,B,C,D,E,F) \
  P##0 =fmaf(xs,A.x,P##0 ); P##1 =fmaf(xs,A.y,P##1 ); P##2 =fmaf(xs,A.z,P##2 ); P##3 =fmaf(xs,A.w,P##3 ); \
  P##4 =fmaf(xs,B.x,P##4 ); P##5 =fmaf(xs,B.y,P##5 ); P##6 =fmaf(xs,B.z,P##6 ); P##7 =fmaf(xs,B.w,P##7 ); \
  P##8 =fmaf(xs,C.x,P##8 ); P##9 =fmaf(xs,C.y,P##9 ); P##10=fmaf(xs,C.z,P##10); P##11=fmaf(xs,C.w,P##11); \
  P##12=fmaf(xs,D.x,P##12); P##13=fmaf(xs,D.y,P##13); P##14=fmaf(xs,D.z,P##14); P##15=fmaf(xs,D.w,P##15); \
  P##16=fmaf(xs,E.x,P##16); P##17=fmaf(xs,E.y,P##17); P##18=fmaf(xs,E.z,P##18); P##19=fmaf(xs,E.w,P##19); \
  P##20=fmaf(xs,F.x,P##20); P##21=fmaf(xs,F.y,P##21); P##22=fmaf(xs,F.z,P##22); P##23=fmaf(xs,F.w,P##23);

// one W-row update: P##0..23 += x##j * W[j][0..23]
#define WJ(j,W,P) { const float xj_ = x##j; LD6(&sm[(W)+(j)*24], wA,wB,wC,wD,wE,wF) \
                    FMA24(P,xj_,wA,wB,wC,wD,wE,wF) }
#define REPW24(W,P) WJ(0,W,P) WJ(1,W,P) WJ(2,W,P) WJ(3,W,P) WJ(4,W,P) WJ(5,W,P) \
  WJ(6,W,P) WJ(7,W,P) WJ(8,W,P) WJ(9,W,P) WJ(10,W,P) WJ(11,W,P) WJ(12,W,P) WJ(13,W,P) \
  WJ(14,W,P) WJ(15,W,P) WJ(16,W,P) WJ(17,W,P) WJ(18,W,P) WJ(19,W,P) WJ(20,W,P) \
  WJ(21,W,P) WJ(22,W,P) WJ(23,W,P)

// ---------------- kernel 0: positional encoding table (transposed [f][s]) ----------------
__global__ void posenc_kernel(float* __restrict__ pe) {
    int i = threadIdx.x;
    if (i < 504) {
        int f = i / 21, s = i % 21;
        double e = (double)(2 * (f / 2)) / 24.0;
        double ang = (double)s / pow(10000.0, e);
        float v = (f & 1) ? cosf((float)ang) : sinf((float)ang);
        pe[i] = 0.01f * v + 0.01f;   // folded *0.01 + 0.01
    }
}

// ---------------- kernel 1: fused per-token transformer, one row per lane ----------------
// waves_per_eu(3,3): occupancy is LDS-bound at 3 blocks/CU (=3 waves/EU), so pin the
// allocator budget to 512/3 ~ 168 VGPRs. Default heuristic capped at 84 and spilled
// ~1.8KB/thread to scratch (observed: VGPR=84, 1.42 GB HBM traffic, VALUBusy 29%).
__global__ __launch_bounds__(256)
__attribute__((amdgpu_waves_per_eu(3, 3)))
void token_kernel(
    const float* __restrict__ inp,
    const float* __restrict__ wq, const float* __restrict__ bq,
    const float* __restrict__ wk, const float* __restrict__ bk,
    const float* __restrict__ wv, const float* __restrict__ bv,
    const float* __restrict__ relk, const float* __restrict__ relv,
    const float* __restrict__ ga, const float* __restrict__ ba,
    const float* __restrict__ w1, const float* __restrict__ b1,
    const float* __restrict__ w2, const float* __restrict__ b2,
    const float* __restrict__ gf, const float* __restrict__ bf,
    const float* __restrict__ pe, float* __restrict__ ffout, int ntok)
{
    __shared__ __align__(16) float sm[SM_TOT];
    const int tid  = threadIdx.x;
    const int lane = tid & 63;
    const int wv_  = tid >> 6;

    // ---- coalesced input staging: wave's 3 tokens (1512 floats) -> LDS tile ----
    {
        const size_t lim4  = (size_t)ntok * 126;
        const size_t base4 = ((size_t)blockIdx.x * 12 + wv_ * 3) * 126;
        const float4* in4 = (const float4*)inp;
        float4* t4 = (float4*)&sm[O_KV + wv_ * 1512];
        #pragma unroll
        for (int c = 0; c < 6; ++c) {
            int idx = lane + c * 64;
            if (idx < 378) {
                float4 v4 = make_float4(0.f, 0.f, 0.f, 0.f);
                if (base4 + idx < lim4) v4 = in4[base4 + idx];
                t4[idx] = v4;
            }
        }
    }

    // ---- cooperative weight staging ----
    for (int i = tid; i < 576; i += 256) { sm[O_WQ+i]=wq[i]; sm[O_WK+i]=wk[i]; sm[O_WV+i]=wv[i]; }
    for (int i = tid; i < 2304; i += 256) { sm[O_W1+i]=w1[i]; sm[O_W2+i]=w2[i]; }
    if (tid < 108) { sm[O_RELK+tid]=relk[tid]; sm[O_RELV+tid]=relv[tid]; }
    if (tid < 24) { sm[O_BQ+tid]=bq[tid]; sm[O_BK+tid]=bk[tid]; sm[O_BV+tid]=bv[tid];
                    sm[O_B2+tid]=b2[tid]; sm[O_GA+tid]=ga[tid]; sm[O_BA+tid]=ba[tid];
                    sm[O_GF+tid]=gf[tid]; sm[O_BF+tid]=bf[tid]; }
    if (tid >= 128 && tid < 224) sm[O_B1+tid-128] = b1[tid-128];
    for (int i = tid; i < 504; i += 256) sm[O_PE+i] = pe[i];
    __syncthreads();

    // ---- lane -> (token t, row s) ----
    int t = lane / 21;
    int s = lane - t * 21;
    if (lane == 63) { t = 2; s = 20; }     // dummy lane mirrors lane 62 (benign dup writes)
    float* tile  = &sm[O_KV + (wv_*3 + t) * 504];
    float* myrow = tile + s * 24;

    // ---- x row from LDS (transposed) + posenc ----
#define DX(i) float x##i = tile[(i)*21 + s] + sm[O_PE + (i)*21 + s];
    REP24(DX)

    // ---- k = relu(x@Wk+bk) -> LDS (overwrites raw input; x already read) ----
    {
#define DKK(i) float kk##i = sm[O_BK+(i)];
        REP24(DKK)
        REPW24(O_WK, kk)
        *(float4*)(myrow+ 0) = make_float4(fmaxf(kk0 ,0.f),fmaxf(kk1 ,0.f),fmaxf(kk2 ,0.f),fmaxf(kk3 ,0.f));
        *(float4*)(myrow+ 4) = make_float4(fmaxf(kk4 ,0.f),fmaxf(kk5 ,0.f),fmaxf(kk6 ,0.f),fmaxf(kk7 ,0.f));
        *(float4*)(myrow+ 8) = make_float4(fmaxf(kk8 ,0.f),fmaxf(kk9 ,0.f),fmaxf(kk10,0.f),fmaxf(kk11,0.f));
        *(float4*)(myrow+12) = make_float4(fmaxf(kk12,0.f),fmaxf(kk13,0.f),fmaxf(kk14,0.f),fmaxf(kk15,0.f));
        *(float4*)(myrow+16) = make_float4(fmaxf(kk16,0.f),fmaxf(kk17,0.f),fmaxf(kk18,0.f),fmaxf(kk19,0.f));
        *(float4*)(myrow+20) = make_float4(fmaxf(kk20,0.f),fmaxf(kk21,0.f),fmaxf(kk22,0.f),fmaxf(kk23,0.f));
    }

    // ---- q = relu(x@Wq+bq) -> named scalars (k-write latency hides under this) ----
#define DQQ(i) float q##i = sm[O_BQ+(i)];
    REP24(DQQ)
    REPW24(O_WQ, q)
#define RQ(i) q##i = fmaxf(q##i, 0.f);
    REP24(RQ)
    asm volatile("s_waitcnt lgkmcnt(0)" ::: "memory");   // wave's k writes visible

    // ---- logits (rel_k row shared by both heads) ----
#define DP_(i) float p0_##i, p1_##i;
    REP21(DP_)
#define LGT(ks) { \
    int dd=(ks)-s; dd=dd<-4?-4:(dd>4?4:dd); dd+=4; \
    const float* kr_ = tile + (ks)*24; \
    const float* rr_ = &sm[O_RELK + dd*12]; \
    LD6(kr_, kA,kB,kC,kD,kE,kF) \
    float4 rA=*(const float4*)(rr_+0), rB=*(const float4*)(rr_+4), rC=*(const float4*)(rr_+8); \
    float a0_=0.f, a1_=0.f; \
    a0_=fmaf(q0 ,kA.x+rA.x,a0_); a0_=fmaf(q1 ,kA.y+rA.y,a0_); a0_=fmaf(q2 ,kA.z+rA.z,a0_); a0_=fmaf(q3 ,kA.w+rA.w,a0_); \
    a0_=fmaf(q4 ,kB.x+rB.x,a0_); a0_=fmaf(q5 ,kB.y+rB.y,a0_); a0_=fmaf(q6 ,kB.z+rB.z,a0_); a0_=fmaf(q7 ,kB.w+rB.w,a0_); \
    a0_=fmaf(q8 ,kC.x+rC.x,a0_); a0_=fmaf(q9 ,kC.y+rC.y,a0_); a0_=fmaf(q10,kC.z+rC.z,a0_); a0_=fmaf(q11,kC.w+rC.w,a0_); \
    a1_=fmaf(q12,kD.x+rA.x,a1_); a1_=fmaf(q13,kD.y+rA.y,a1_); a1_=fmaf(q14,kD.z+rA.z,a1_); a1_=fmaf(q15,kD.w+rA.w,a1_); \
    a1_=fmaf(q16,kE.x+rB.x,a1_); a1_=fmaf(q17,kE.y+rB.y,a1_); a1_=fmaf(q18,kE.z+rB.z,a1_); a1_=fmaf(q19,kE.w+rB.w,a1_); \
    a1_=fmaf(q20,kF.x+rC.x,a1_); a1_=fmaf(q21,kF.y+rC.y,a1_); a1_=fmaf(q22,kF.z+rC.z,a1_); a1_=fmaf(q23,kF.w+rC.w,a1_); \
    p0_##ks = a0_*0.28867513459481287f; p1_##ks = a1_*0.28867513459481287f; }
    REP21(LGT)

    // ---- softmax (straight-line, both heads) ----
    {
        float m0 = p0_0, m1 = p1_0;
#define MX(i) m0 = fmaxf(m0, p0_##i); m1 = fmaxf(m1, p1_##i);
        REP21(MX)
        float sum0 = 0.f, sum1 = 0.f;
#define EX(i) p0_##i = __expf(p0_##i - m0); sum0 += p0_##i; \
              p1_##i = __expf(p1_##i - m1); sum1 += p1_##i;
        REP21(EX)
        float is0 = 1.f/sum0, is1 = 1.f/sum1;
#define NM(i) p0_##i *= is0; p1_##i *= is1;
        REP21(NM)
    }

    // ---- v = relu(x@Wv+bv) -> LDS (k reads retired; in-order DS + waitcnt) ----
    asm volatile("s_waitcnt lgkmcnt(0)" ::: "memory");
    {
#define DVV(i) float vv##i = sm[O_BV+(i)];
        REP24(DVV)
        REPW24(O_WV, vv)
        *(float4*)(myrow+ 0) = make_float4(fmaxf(vv0 ,0.f),fmaxf(vv1 ,0.f),fmaxf(vv2 ,0.f),fmaxf(vv3 ,0.f));
        *(float4*)(myrow+ 4) = make_float4(fmaxf(vv4 ,0.f),fmaxf(vv5 ,0.f),fmaxf(vv6 ,0.f),fmaxf(vv7 ,0.f));
        *(float4*)(myrow+ 8) = make_float4(fmaxf(vv8 ,0.f),fmaxf(vv9 ,0.f),fmaxf(vv10,0.f),fmaxf(vv11,0.f));
        *(float4*)(myrow+12) = make_float4(fmaxf(vv12,0.f),fmaxf(vv13,0.f),fmaxf(vv14,0.f),fmaxf(vv15,0.f));
        *(float4*)(myrow+16) = make_float4(fmaxf(vv16,0.f),fmaxf(vv17,0.f),fmaxf(vv18,0.f),fmaxf(vv19,0.f));
        *(float4*)(myrow+20) = make_float4(fmaxf(vv20,0.f),fmaxf(vv21,0.f),fmaxf(vv22,0.f),fmaxf(vv23,0.f));
    }
    asm volatile("s_waitcnt lgkmcnt(0)" ::: "memory");

    // ---- o = p · (v + rel_v) ----
#define DO_(i) float o##i = 0.f;
    REP24(DO_)
#define OT(ks) { \
    int dd=(ks)-s; dd=dd<-4?-4:(dd>4?4:dd); dd+=4; \
    const float* vr_ = tile + (ks)*24; \
    const float* rr_ = &sm[O_RELV + dd*12]; \
    LD6(vr_, vA,vB,vC,vD,vE,vF) \
    float4 rA=*(const float4*)(rr_+0), rB=*(const float4*)(rr_+4), rC=*(const float4*)(rr_+8); \
    const float w0_ = p0_##ks, w1_ = p1_##ks; \
    o0 =fmaf(w0_,vA.x+rA.x,o0 ); o1 =fmaf(w0_,vA.y+rA.y,o1 ); o2 =fmaf(w0_,vA.z+rA.z,o2 ); o3 =fmaf(w0_,vA.w+rA.w,o3 ); \
    o4 =fmaf(w0_,vB.x+rB.x,o4 ); o5 =fmaf(w0_,vB.y+rB.y,o5 ); o6 =fmaf(w0_,vB.z+rB.z,o6 ); o7 =fmaf(w0_,vB.w+rB.w,o7 ); \
    o8 =fmaf(w0_,vC.x+rC.x,o8 ); o9 =fmaf(w0_,vC.y+rC.y,o9 ); o10=fmaf(w0_,vC.z+rC.z,o10); o11=fmaf(w0_,vC.w+rC.w,o11); \
    o12=fmaf(w1_,vD.x+rA.x,o12); o13=fmaf(w1_,vD.y+rA.y,o13); o14=fmaf(w1_,vD.z+rA.z,o14); o15=fmaf(w1_,vD.w+rA.w,o15); \
    o16=fmaf(w1_,vE.x+rB.x,o16); o17=fmaf(w1_,vE.y+rB.y,o17); o18=fmaf(w1_,vE.z+rB.z,o18); o19=fmaf(w1_,vE.w+rB.w,o19); \
    o20=fmaf(w1_,vF.x+rC.x,o20); o21=fmaf(w1_,vF.y+rC.y,o21); o22=fmaf(w1_,vF.z+rC.z,o22); o23=fmaf(w1_,vF.w+rC.w,o23); }
    REP21(OT)

    // ---- attn = LN(o + x), lane-local ----
#define ATD(i) float at##i = o##i + x##i;
    REP24(ATD)
    {
        float sA = 0.f, sB = 0.f;
#define ASUM(i) sA += at##i; sB = fmaf(at##i, at##i, sB);
        REP24(ASUM)
        float mn = sA * (1.f/24.f);
        float rstd = rsqrtf(sB*(1.f/24.f) - mn*mn + 1e-3f);
#define ALN(i) at##i = fmaf(sm[O_GA+(i)], (at##i - mn)*rstd, sm[O_BA+(i)]);
        REP24(ALN)
    }

    // ---- ff = relu(at@w1+b1)@w2 + b2, hidden in 24-wide chunks ----
#define DFF(i) float ff##i = sm[O_B2+(i)];
    REP24(DFF)
    for (int cc = 0; cc < 96; cc += 24) {
#define DH2(i) float h##i = sm[O_B1 + cc + (i)];
        REP24(DH2)
#define HJ(j) { const float aj_ = at##j; LD6(&sm[O_W1+(j)*96+cc], wA,wB,wC,wD,wE,wF) \
                FMA24(h,aj_,wA,wB,wC,wD,wE,wF) }
        REP24(HJ)
#define RH(i) h##i = fmaxf(h##i, 0.f);
        REP24(RH)
#define FL(l) { const float hl_ = h##l; LD6(&sm[O_W2+(cc+(l))*24], wA,wB,wC,wD,wE,wF) \
                FMA24(ff,hl_,wA,wB,wC,wD,wE,wF) }
        REP24(FL)
    }

    // ---- ff = LN(ff + at) ----
    {
#define FR(i) ff##i += at##i;
        REP24(FR)
        float sC = 0.f, sD = 0.f;
#define FSUM(i) sC += ff##i; sD = fmaf(ff##i, ff##i, sD);
        REP24(FSUM)
        float mn2 = sC * (1.f/24.f);
        float rstd2 = rsqrtf(sD*(1.f/24.f) - mn2*mn2 + 1e-3f);
#define FLN(i) ff##i = fmaf(sm[O_GF+(i)], (ff##i - mn2)*rstd2, sm[O_BF+(i)]);
        REP24(FLN)
    }

    // ---- transpose via tile (v reads all retired), then coalesced store ----
#define STF(i) tile[(i)*21 + s] = ff##i;
    REP24(STF)
    asm volatile("s_waitcnt lgkmcnt(0)" ::: "memory");
    {
        const size_t lim4  = (size_t)ntok * 126;
        const size_t base4 = ((size_t)blockIdx.x * 12 + wv_ * 3) * 126;
        float4* out4 = (float4*)ffout;
        const float4* t4 = (const float4*)&sm[O_KV + wv_ * 1512];
        #pragma unroll
        for (int c = 0; c < 6; ++c) {
            int idx = lane + c * 64;
            if (idx < 378 && base4 + idx < lim4)
                out4[base4 + idx] = t4[idx];
        }
    }
}

// ---------------- kernel 2: [N,504]@[504,512] + bias + relu (LN done separately) ----------------
// waves_per_eu(2,2): LDS-bound at 2 blocks/CU (=2 waves/EU) -> 256-VGPR budget,
// room for acc[8][16]+temps without heuristic capping.
#define DB_LDA 68
__global__ __launch_bounds__(256)
__attribute__((amdgpu_waves_per_eu(2, 2)))
void dense_kernel(
    const float* __restrict__ A, const float* __restrict__ wd,
    const float* __restrict__ bd, float* __restrict__ out)
{
    __shared__ __align__(16) float At[24*DB_LDA];   // 1632 floats
    __shared__ __align__(16) float Bs[24*512];      // 12288 floats
    const int tid  = threadIdx.x;
    const int w    = tid >> 6;
    const int lane = tid & 63;
    const int lr   = lane >> 3;
    const int lc   = lane & 7;
    const int row0 = blockIdx.x * 64;
    const int colb = w*128 + lc*4;   // + cb*32

    float acc[8][16];
    #pragma unroll
    for (int r = 0; r < 8; ++r)
        #pragma unroll
        for (int j = 0; j < 16; ++j) acc[r][j] = 0.f;

    for (int k0 = 0; k0 < 504; k0 += 24) {
        __syncthreads();
        #pragma unroll
        for (int i = 0; i < 6; ++i) {
            int ii = tid + i*256;                 // 1536 = 64 rows x 24 kk
            int r = ii / 24, kk = ii - r*24;
            At[kk*DB_LDA + r] = A[(size_t)(row0 + r)*504 + k0 + kk];
        }
        const float4* Bg = (const float4*)(wd + k0*512);
        float4* Bs4 = (float4*)Bs;
        #pragma unroll
        for (int i = 0; i < 12; ++i) Bs4[tid + i*256] = Bg[tid + i*256];
        __syncthreads();

        #pragma unroll 4
        for (int kk = 0; kk < 24; ++kk) {
            float4 a0 = *(const float4*)&At[kk*DB_LDA + lr*8];
            float4 a1 = *(const float4*)&At[kk*DB_LDA + lr*8 + 4];
            float av[8] = {a0.x,a0.y,a0.z,a0.w,a1.x,a1.y,a1.z,a1.w};
            float bv[16];
            #pragma unroll
            for (int cb = 0; cb < 4; ++cb) {
                float4 b4 = *(const float4*)&Bs[kk*512 + colb + cb*32];
                bv[cb*4+0]=b4.x; bv[cb*4+1]=b4.y; bv[cb*4+2]=b4.z; bv[cb*4+3]=b4.w;
            }
            #pragma unroll
            for (int r = 0; r < 8; ++r)
                #pragma unroll
                for (int j = 0; j < 16; ++j)
                    acc[r][j] = fmaf(av[r], bv[j], acc[r][j]);
        }
    }

    float4 bias[4];
    #pragma unroll
    for (int cb = 0; cb < 4; ++cb) bias[cb] = *(const float4*)&bd[colb + cb*32];
    #pragma unroll
    for (int r = 0; r < 8; ++r) {
        float* orow = out + (size_t)(row0 + lr*8 + r)*512;
        #pragma unroll
        for (int cb = 0; cb < 4; ++cb) {
            float4 o4;
            o4.x = fmaxf(acc[r][cb*4+0] + bias[cb].x, 0.f);
            o4.y = fmaxf(acc[r][cb*4+1] + bias[cb].y, 0.f);
            o4.z = fmaxf(acc[r][cb*4+2] + bias[cb].z, 0.f);
            o4.w = fmaxf(acc[r][cb*4+3] + bias[cb].w, 0.f);
            *(float4*)&orow[colb + cb*32] = o4;
        }
    }
}

// ---------------- kernel 3: in-place LN over 512 cols, one row per wave ----------------
__global__ __launch_bounds__(256, 4) void ln512_kernel(
    float* __restrict__ out, const float* __restrict__ g, const float* __restrict__ b)
{
    const int lane = threadIdx.x & 63;
    const size_t row = (size_t)blockIdx.x * 4 + (threadIdx.x >> 6);
    float4* p = (float4*)(out + row*512) + lane*2;
    float4 v0 = p[0], v1 = p[1];
    float s1 = v0.x+v0.y+v0.z+v0.w + v1.x+v1.y+v1.z+v1.w;
    float s2 = 0.f;
    s2 = fmaf(v0.x,v0.x,s2); s2 = fmaf(v0.y,v0.y,s2); s2 = fmaf(v0.z,v0.z,s2); s2 = fmaf(v0.w,v0.w,s2);
    s2 = fmaf(v1.x,v1.x,s2); s2 = fmaf(v1.y,v1.y,s2); s2 = fmaf(v1.z,v1.z,s2); s2 = fmaf(v1.w,v1.w,s2);
    #pragma unroll
    for (int off = 32; off > 0; off >>= 1) {
        s1 += __shfl_xor(s1, off);
        s2 += __shfl_xor(s2, off);
    }
    float m  = s1 * (1.f/512.f);
    float rs = rsqrtf(s2 * (1.f/512.f) - m*m + 1e-3f);
    const float4* g4 = (const float4*)g + lane*2;
    const float4* b4 = (const float4*)b + lane*2;
    float4 ga0 = g4[0], ga1 = g4[1], bb0 = b4[0], bb1 = b4[1];
    v0.x = fmaf(ga0.x, (v0.x-m)*rs, bb0.x);
    v0.y = fmaf(ga0.y, (v0.y-m)*rs, bb0.y);
    v0.z = fmaf(ga0.z, (v0.z-m)*rs, bb0.z);
    v0.w = fmaf(ga0.w, (v0.w-m)*rs, bb0.w);
    v1.x = fmaf(ga1.x, (v1.x-m)*rs, bb1.x);
    v1.y = fmaf(ga1.y, (v1.y-m)*rs, bb1.y);
    v1.z = fmaf(ga1.z, (v1.z-m)*rs, bb1.z);
    v1.w = fmaf(ga1.w, (v1.w-m)*rs, bb1.w);
    p[0] = v0; p[1] = v1;
}

extern "C" void kernel_launch(void* const* d_in, const int* in_sizes, int n_in,
                              void* d_out, int out_size, void* d_ws, size_t ws_size,
                              hipStream_t stream)
{
    const float* inp  = (const float*)d_in[0];
    const float* wq   = (const float*)d_in[1];
    const float* bq   = (const float*)d_in[2];
    const float* wk   = (const float*)d_in[3];
    const float* bk   = (const float*)d_in[4];
    const float* wv   = (const float*)d_in[5];
    const float* bv   = (const float*)d_in[6];
    const float* relk = (const float*)d_in[7];
    const float* relv = (const float*)d_in[8];
    const float* ga   = (const float*)d_in[9];
    const float* ba   = (const float*)d_in[10];
    const float* w1   = (const float*)d_in[11];
    const float* b1   = (const float*)d_in[12];
    const float* w2   = (const float*)d_in[13];
    const float* b2   = (const float*)d_in[14];
    const float* gf   = (const float*)d_in[15];
    const float* bf   = (const float*)d_in[16];
    const float* wd   = (const float*)d_in[17];
    const float* bd   = (const float*)d_in[18];
    const float* go_  = (const float*)d_in[19];
    const float* bo_  = (const float*)d_in[20];

    float* ws = (float*)d_ws;
    float* pe = ws;             // 504 floats (transposed [f][s])
    float* ff = ws + 512;       // N*504 floats
    const int N = in_sizes[0] / 504;   // 32768

    hipLaunchKernelGGL(posenc_kernel, dim3(1), dim3(512), 0, stream, pe);
    hipLaunchKernelGGL(token_kernel, dim3((N + 11) / 12), dim3(256), 0, stream,
                       inp, wq, bq, wk, bk, wv, bv, relk, relv, ga, ba,
                       w1, b1, w2, b2, gf, bf, pe, ff, N);
    hipLaunchKernelGGL(dense_kernel, dim3(N/64), dim3(256), 0, stream,
                       ff, wd, bd, (float*)d_out);
    hipLaunchKernelGGL(ln512_kernel, dim3(N/4), dim3(256), 0, stream,
                       (float*)d_out, go_, bo_);
}